// Round 1
// baseline (328.411 us; speedup 1.0000x reference)
//
#include <hip/hip_runtime.h>

#define BATCH 131072
#define UNITS 512
#define DIM   64
#define BM    128

typedef __attribute__((ext_vector_type(8))) short  short8;
typedef __attribute__((ext_vector_type(4))) float  floatx4;

static __device__ __forceinline__ unsigned short f32_to_bf16(float f) {
    union { float f; unsigned int u; } c; c.f = f;
    unsigned int u = c.u;
    unsigned int r = u + 0x7fffu + ((u >> 16) & 1u);   // round-nearest-even
    return (unsigned short)(r >> 16);
}

// Convert w [512][64] fp32 -> bf16, and per-row sum of squares.
__global__ __launch_bounds__(256) void prep_w_kernel(
    const float* __restrict__ w,
    unsigned short* __restrict__ wb,
    float* __restrict__ wsq)
{
    const int u = blockIdx.x * 4 + (threadIdx.x >> 6);   // one wave per w-row
    const int d = threadIdx.x & 63;
    float v = w[u * DIM + d];
    wb[u * DIM + d] = f32_to_bf16(v);
    float s = v * v;
    #pragma unroll
    for (int o = 32; o > 0; o >>= 1) s += __shfl_xor(s, o);
    if (d == 0) wsq[u] = s;
}

// dist[b,u] = ||x_b||^2 + ||w_u||^2 - 2 * x_b . w_u
//
// SWAPPED-OPERAND epilogue: operand layouts for mfma_f32_16x16x32_bf16 are
// symmetric (both A and B frags: row index = lane&15, k = quad*8+j — this is
// exactly how the previously-verified kernel loaded both). So
// mfma(b_frag, a_frag) computes the transposed tile:
//   lane(quad,l15) holds D[u = quad*4+i][b = l15]
// => each lane's 4 acc values are 4 CONSECUTIVE u-columns of one output row
// => direct floatx4 nontemporal store from registers. No LDS round-trip,
//    no ds_write->lgkmcnt->ds_read chain, no staging barrier.
//
// x is loaded directly per-fragment (each lane loads exactly its own 16
// floats, coalesced 16B granules), converted to bf16 in-register; the row
// sum-of-squares is completed by 2 shfl_xor across the 4 lanes sharing l15.
__global__ __launch_bounds__(256) void dist_kernel(
    const float* __restrict__ x,
    const unsigned short* __restrict__ wb,
    const float* __restrict__ wsq,
    float* __restrict__ out)
{
    __shared__ __align__(16) float wsq_s[UNITS];       // 2 KB — only LDS left

    const int tid  = threadIdx.x;
    const int row0 = blockIdx.x * BM;

    wsq_s[tid]       = wsq[tid];
    wsq_s[tid + 256] = wsq[tid + 256];
    __syncthreads();

    const int wave = tid >> 6;
    const int lane = tid & 63;
    const int l15  = lane & 15;
    const int quad = lane >> 4;
    const int mrow = wave * 32;                        // 32 x-rows per wave

    // ---- A-frags straight from global: lane = row (mrow+mf*16+l15),
    //      k = quad*8+j (half 0: k in [0,32), half 1: k in [32,64)) ----
    short8 a[2][2];
    float  xs2[2];
    #pragma unroll
    for (int mf = 0; mf < 2; ++mf) {
        const float* xr = x + (size_t)(row0 + mrow + mf * 16 + l15) * DIM;
        float v[16];
        *(float4*)&v[0]  = *(const float4*)(xr + quad * 8);
        *(float4*)&v[4]  = *(const float4*)(xr + quad * 8 + 4);
        *(float4*)&v[8]  = *(const float4*)(xr + 32 + quad * 8);
        *(float4*)&v[12] = *(const float4*)(xr + 32 + quad * 8 + 4);
        float s = 0.f;
        unsigned short p[16];
        #pragma unroll
        for (int i = 0; i < 16; ++i) { s += v[i] * v[i]; p[i] = f32_to_bf16(v[i]); }
        a[mf][0] = *(short8*)&p[0];
        a[mf][1] = *(short8*)&p[8];
        // 4 lanes sharing l15 (quads 0..3) jointly hold all 64 elems of the row
        s += __shfl_xor(s, 16);
        s += __shfl_xor(s, 32);
        xs2[mf] = s;
    }

    const short8* wv = (const short8*)wb;              // w rows as groups of 8 bf16

    for (int gu = 0; gu < 8; ++gu) {                   // 8 groups of 64 u-cols
        const int colb = gu * 64;

        // B-frags: lane = w-row (colb+t*16+l15), k = quad*8+j, two k-halves
        short8  b[4][2];
        floatx4 wq[4];                                 // wsq[u] for u = colb+t*16+quad*4+i
        #pragma unroll
        for (int t = 0; t < 4; ++t) {
            const short8* bp = wv + (size_t)(colb + t * 16 + l15) * 8;
            b[t][0] = bp[quad];
            b[t][1] = bp[quad + 4];
            wq[t]   = *(const floatx4*)&wsq_s[colb + t * 16 + quad * 4];
        }

        #pragma unroll
        for (int mf = 0; mf < 2; ++mf) {
            #pragma unroll
            for (int t = 0; t < 4; ++t) {
                floatx4 acc = floatx4{0.f, 0.f, 0.f, 0.f};
                // swapped operands -> transposed tile
                acc = __builtin_amdgcn_mfma_f32_16x16x32_bf16(b[t][0], a[mf][0], acc, 0, 0, 0);
                acc = __builtin_amdgcn_mfma_f32_16x16x32_bf16(b[t][1], a[mf][1], acc, 0, 0, 0);

                floatx4 vo;
                #pragma unroll
                for (int i = 0; i < 4; ++i)
                    vo[i] = xs2[mf] + wq[t][i] - 2.0f * acc[i];

                // lane stores 4 consecutive u's of row (row0+mrow+mf*16+l15):
                // per instruction: 16 rows x 64 B contiguous segments
                float* dst = out + (size_t)(row0 + mrow + mf * 16 + l15) * UNITS
                                 + colb + t * 16 + quad * 4;
                __builtin_nontemporal_store(vo, (floatx4*)dst);
            }
        }
    }
}

extern "C" void kernel_launch(void* const* d_in, const int* in_sizes, int n_in,
                              void* d_out, int out_size, void* d_ws, size_t ws_size,
                              hipStream_t stream) {
    const float* x = (const float*)d_in[0];
    const float* w = (const float*)d_in[1];
    float* out = (float*)d_out;

    unsigned short* wb  = (unsigned short*)d_ws;                       // 64 KB
    float*          wsq = (float*)((char*)d_ws + UNITS * DIM * 2);     // 2 KB

    prep_w_kernel<<<UNITS / 4, 256, 0, stream>>>(w, wb, wsq);
    dist_kernel<<<BATCH / BM, 256, 0, stream>>>(x, wb, wsq, out);
}